// Round 1
// baseline (1977.853 us; speedup 1.0000x reference)
//
#include <hip/hip_runtime.h>
#include <cstddef>

// Problem constants (fixed by the reference)
constexpr int NUM_ENT_C = 10000;
constexpr int SEQ_C     = 10;
constexpr int H_C       = 200;   // hidden dim
constexpr int OUT_C     = 100;   // word-embed / mid dim
constexpr int NG_C      = 2048;
constexpr int NREL_C    = 240;
constexpr int MQ_C      = 8;

// ---------------------------------------------------------------------------
// Elementwise / gather / scatter kernels
// ---------------------------------------------------------------------------

template<int D, bool MOD>
__global__ void gather_rows_k(const float* __restrict__ src, const int* __restrict__ idx,
                              float* __restrict__ dst, int n) {
    size_t total  = (size_t)n * D;
    size_t stride = (size_t)gridDim.x * blockDim.x;
    for (size_t t = (size_t)blockIdx.x * blockDim.x + threadIdx.x; t < total; t += stride) {
        size_t i = t / D;
        int d = (int)(t - i * D);
        int r = idx[i];
        if (MOD) r = r % NUM_ENT_C;
        dst[t] = src[(size_t)r * D + d];
    }
}

__global__ void count_k(const int* __restrict__ dIdx, float* __restrict__ cnt, int E) {
    int stride = gridDim.x * blockDim.x;
    for (int t = blockIdx.x * blockDim.x + threadIdx.x; t < E; t += stride)
        atomicAdd(&cnt[dIdx[t]], 1.0f);
}

__global__ void inv_k(float* __restrict__ c, int n) {
    int stride = gridDim.x * blockDim.x;
    for (int t = blockIdx.x * blockDim.x + threadIdx.x; t < n; t += stride)
        c[t] = 1.0f / fmaxf(c[t], 1.0f);
}

// out[dIdx[e]*D+d] += feat[sIdx[e]*D+d]
template<int D>
__global__ void scatter_add_k(const float* __restrict__ feat, const int* __restrict__ sIdx,
                              const int* __restrict__ dIdx, float* __restrict__ out, int E) {
    size_t total  = (size_t)E * D;
    size_t stride = (size_t)gridDim.x * blockDim.x;
    for (size_t t = (size_t)blockIdx.x * blockDim.x + threadIdx.x; t < total; t += stride) {
        size_t e = t / D;
        int d = (int)(t - e * D);
        atomicAdd(&out[(size_t)dIdx[e] * D + d], feat[(size_t)sIdx[e] * D + d]);
    }
}

// out[dIdx[e]*D+d] += hfeat[sIdx[e]*D+d] - rel[tIdx[e]*D+d]
template<int D>
__global__ void scatter_add_sub_k(const float* __restrict__ hfeat, const float* __restrict__ rel,
                                  const int* __restrict__ sIdx, const int* __restrict__ dIdx,
                                  const int* __restrict__ tIdx, float* __restrict__ out, int E) {
    size_t total  = (size_t)E * D;
    size_t stride = (size_t)gridDim.x * blockDim.x;
    for (size_t t = (size_t)blockIdx.x * blockDim.x + threadIdx.x; t < total; t += stride) {
        size_t e = t / D;
        int d = (int)(t - e * D);
        float v = hfeat[(size_t)sIdx[e] * D + d] - rel[(size_t)tIdx[e] * D + d];
        atomicAdd(&out[(size_t)dIdx[e] * D + d], v);
    }
}

// Q[m,:] = (m < N) ? h2[m,:] : rel2[edge_type[r_ids[m-N]],:]
__global__ void build_q_k(const float* __restrict__ h2, const float* __restrict__ rel2,
                          const int* __restrict__ edge_type, const int* __restrict__ r_ids,
                          float* __restrict__ Q, int N, int M) {
    size_t total  = (size_t)M * H_C;
    size_t stride = (size_t)gridDim.x * blockDim.x;
    for (size_t t = (size_t)blockIdx.x * blockDim.x + threadIdx.x; t < total; t += stride) {
        size_t m = t / H_C;
        int d = (int)(t - m * H_C);
        if ((int)m < N) {
            Q[t] = h2[t];
        } else {
            int rr = r_ids[(int)m - N];
            Q[t] = rel2[(size_t)edge_type[rr] * H_C + d];
        }
    }
}

// row -> flat offset into d_out (embed_seq first, then node_emb_temporal)
__global__ void rowoff_k(const int* __restrict__ node_slot, const int* __restrict__ edge_slot,
                         int* __restrict__ rowOff, int N, int M, int divq, int per, int embBase) {
    int stride = gridDim.x * blockDim.x;
    for (int m = blockIdx.x * blockDim.x + threadIdx.x; m < M; m += stride) {
        int off;
        if (m < N) {
            int ns = node_slot[m];
            int nid  = ns % NUM_ENT_C;
            int gidx = ns / divq;
            off = embBase + (nid * SEQ_C + gidx) * H_C;
        } else {
            int es  = edge_slot[m - N];
            int row = es / per;
            int pos = es - row * per;
            off = (row * SEQ_C + pos) * H_C;
        }
        rowOff[m] = off;
    }
}

// ---------------------------------------------------------------------------
// Tiled GEMM: C[M,N] = act( A[M,K]*scale(row) @ W[K,N] (+ A2[M,K] @ W2[K,N]) (+ bias[N]) )
// SCATTER: store at C[rowOff[m] + n] instead of C[m*N + n]
// ---------------------------------------------------------------------------
template<int ACT, bool DUAL, bool SCATTER>
__global__ __launch_bounds__(256) void gemm_k(
        const float* __restrict__ A, const float* __restrict__ W,
        const float* __restrict__ rowScale,
        const float* __restrict__ A2, const float* __restrict__ W2,
        const float* __restrict__ bias,
        float* __restrict__ C, const int* __restrict__ rowOff,
        int M, int N, int K) {
    constexpr int TS = 64, BK = 16;
    __shared__ float As[BK][TS];
    __shared__ float Bs[BK][TS];
    int bm = blockIdx.x * TS;
    int bn = blockIdx.y * TS;
    int tid = threadIdx.x;
    int tx = tid & 15, ty = tid >> 4;
    float acc[4][4] = {};
    const int passes = DUAL ? 2 : 1;
    for (int p = 0; p < passes; ++p) {
        const float* Ap = (DUAL && p) ? A2 : A;
        const float* Wp = (DUAL && p) ? W2 : W;
        const float* sc = (p == 0) ? rowScale : nullptr;
        for (int k0 = 0; k0 < K; k0 += BK) {
            // A tile (TS x BK) -> As[k][m]
            #pragma unroll
            for (int l = tid; l < TS * BK; l += 256) {
                int m = l >> 4, kk = l & 15;
                int gm = bm + m, gk = k0 + kk;
                float v = 0.f;
                if (gm < M && gk < K) {
                    v = Ap[(size_t)gm * K + gk];
                    if (sc) v *= sc[gm];
                }
                As[kk][m] = v;
            }
            // W tile (BK x TS) -> Bs[k][n]
            #pragma unroll
            for (int l = tid; l < TS * BK; l += 256) {
                int kk = l >> 6, n = l & 63;
                int gk = k0 + kk, gn = bn + n;
                float v = 0.f;
                if (gk < K && gn < N) v = Wp[(size_t)gk * N + gn];
                Bs[kk][n] = v;
            }
            __syncthreads();
            #pragma unroll
            for (int kk = 0; kk < BK; ++kk) {
                float a[4], b[4];
                #pragma unroll
                for (int i = 0; i < 4; ++i) a[i] = As[kk][ty * 4 + i];
                #pragma unroll
                for (int j = 0; j < 4; ++j) b[j] = Bs[kk][tx * 4 + j];
                #pragma unroll
                for (int i = 0; i < 4; ++i)
                    #pragma unroll
                    for (int j = 0; j < 4; ++j)
                        acc[i][j] += a[i] * b[j];
            }
            __syncthreads();
        }
    }
    #pragma unroll
    for (int i = 0; i < 4; ++i) {
        int gm = bm + ty * 4 + i;
        if (gm >= M) continue;
        size_t base = SCATTER ? (size_t)rowOff[gm] : (size_t)gm * N;
        #pragma unroll
        for (int j = 0; j < 4; ++j) {
            int gn = bn + tx * 4 + j;
            if (gn >= N) continue;
            float v = acc[i][j];
            if (bias) v += bias[gn];
            if (ACT == 1) v = fmaxf(v, 0.f);
            if (ACT == 2) v = tanhf(v);
            C[base + gn] = v;
        }
    }
}

template<int ACT, bool DUAL, bool SCATTER>
static void launch_gemm(hipStream_t s, const float* A, const float* W, const float* scale,
                        const float* A2, const float* W2, const float* bias,
                        float* C, const int* rowOff, int M, int N, int K) {
    dim3 g((M + 63) / 64, (N + 63) / 64);
    gemm_k<ACT, DUAL, SCATTER><<<g, 256, 0, s>>>(A, W, scale, A2, W2, bias, C, rowOff, M, N, K);
}

// ---------------------------------------------------------------------------
// Attention: scores (8 masked dots) -> softmax (incl. zero scores) -> ctx
// One wave (64 lanes) per row m. ctx overwrites QA in place.
// ---------------------------------------------------------------------------
__global__ __launch_bounds__(256) void attn_k(
        float* __restrict__ QActx, const float* __restrict__ wh,
        const int* __restrict__ ent_idx, const int* __restrict__ ent_mask,
        const int* __restrict__ rel_idx, const int* __restrict__ rel_mask,
        int N, int M) {
    int wave = (int)(((size_t)blockIdx.x * blockDim.x + threadIdx.x) >> 6);
    int lane = threadIdx.x & 63;
    if (wave >= M) return;
    int m = wave;
    const int* idxp;
    const int* mskp;
    if (m < N) { idxp = ent_idx + (size_t)m * MQ_C;        mskp = ent_mask + (size_t)m * MQ_C; }
    else       { idxp = rel_idx + (size_t)(m - N) * MQ_C;  mskp = rel_mask + (size_t)(m - N) * MQ_C; }

    float qa[4];
    #pragma unroll
    for (int j = 0; j < 4; ++j) {
        int d = j * 64 + lane;
        qa[j] = (d < H_C) ? QActx[(size_t)m * H_C + d] : 0.f;
    }
    int   idx[MQ_C];
    float msk[MQ_C];
    float s[MQ_C];
    #pragma unroll
    for (int k = 0; k < MQ_C; ++k) { idx[k] = idxp[k]; msk[k] = (float)mskp[k]; }
    #pragma unroll
    for (int k = 0; k < MQ_C; ++k) {
        const float* w = wh + (size_t)idx[k] * H_C;
        float p = 0.f;
        #pragma unroll
        for (int j = 0; j < 4; ++j) {
            int d = j * 64 + lane;
            if (d < H_C) p += qa[j] * w[d];
        }
        #pragma unroll
        for (int off = 32; off; off >>= 1) p += __shfl_xor(p, off);
        s[k] = p * msk[k];   // masked slot -> exact 0, matches reference
    }
    float mx = s[0];
    #pragma unroll
    for (int k = 1; k < MQ_C; ++k) mx = fmaxf(mx, s[k]);
    float den = 0.f;
    #pragma unroll
    for (int k = 0; k < MQ_C; ++k) { s[k] = expf(s[k] - mx); den += s[k]; }
    float inv = 1.f / den;
    #pragma unroll
    for (int j = 0; j < 4; ++j) {
        int d = j * 64 + lane;
        if (d >= H_C) continue;
        float c = 0.f;
        #pragma unroll
        for (int k = 0; k < MQ_C; ++k) c += s[k] * msk[k] * wh[(size_t)idx[k] * H_C + d];
        QActx[(size_t)m * H_C + d] = c * inv;
    }
}

// ---------------------------------------------------------------------------

static inline dim3 ew_grid(size_t total) {
    size_t b = (total + 255) / 256;
    if (b > 4096) b = 4096;
    return dim3((unsigned)b);
}

extern "C" void kernel_launch(void* const* d_in, const int* in_sizes, int n_in,
                              void* d_out, int out_size, void* d_ws, size_t ws_size,
                              hipStream_t stream) {
    // ---- inputs (setup_inputs order)
    const float* ent_embeds = (const float*)d_in[0];
    const float* rel_embeds = (const float*)d_in[1];
    const float* word_embeds= (const float*)d_in[2];
    const float* gcn_w1     = (const float*)d_in[3];
    const float* gcn_b1     = (const float*)d_in[4];
    const float* gcn_w2     = (const float*)d_in[5];
    const float* gcn_b2     = (const float*)d_in[6];
    const float* cg1_wn     = (const float*)d_in[7];
    const float* cg1_wl     = (const float*)d_in[8];
    const float* cg1_wr     = (const float*)d_in[9];
    const float* cg2_wn     = (const float*)d_in[10];
    const float* cg2_wl     = (const float*)d_in[11];
    const float* cg2_wr     = (const float*)d_in[12];
    const float* attn_wa    = (const float*)d_in[13];
    const float* attn_wc    = (const float*)d_in[14];
    const int* node_slot    = (const int*)d_in[15];
    const int* edge_src     = (const int*)d_in[16];
    const int* edge_dst     = (const int*)d_in[17];
    const int* edge_type    = (const int*)d_in[18];
    const int* word_id      = (const int*)d_in[19];
    const int* wsrc         = (const int*)d_in[20];
    const int* wdst         = (const int*)d_in[21];
    const int* ent_word_idx = (const int*)d_in[22];
    const int* ent_word_mask= (const int*)d_in[23];
    const int* rel_word_idx = (const int*)d_in[24];
    const int* rel_word_mask= (const int*)d_in[25];
    const int* r_ids_graph  = (const int*)d_in[26];
    const int* edge_slot    = (const int*)d_in[27];

    const int N    = in_sizes[15];          // 50000
    const int E    = in_sizes[16];          // 200000
    const int Nw   = in_sizes[19];          // 30000
    const int Ew   = in_sizes[20];          // 300000
    const int Rsel = in_sizes[27];          // 8192
    const int M    = N + Rsel;              // 58192
    const int divq = N / SEQ_C;             // 5000
    const int per  = Rsel / NG_C;           // 4
    const int embBase = NG_C * SEQ_C * H_C; // 4,096,000

    // ---- workspace carving (floats); total ~159.4 MB
    float* ws = (float*)d_ws;
    size_t o = 0;
    float* wcnt = ws + o; o += Nw;                 // seg counts -> inverse (in place)
    float* ecnt = ws + o; o += N;
    float* rel1 = ws + o; o += (size_t)NREL_C * OUT_C;
    float* rel2 = ws + o; o += (size_t)NREL_C * H_C;
    int*   rowOff = (int*)(ws + o); o += M;
    float* wh   = ws + o; o += (size_t)Nw * H_C;   // final word features (long-lived)
    float* h2   = ws + o; o += (size_t)N * H_C;    // final entity features (long-lived)
    float* QA   = ws + o; o += (size_t)M * H_C;    // Q@wa, then ctx in place
    float* BIG  = ws + o;                          // 12M floats, phase-local reuse
    // phase W layout in BIG:
    float* wh0  = BIG;                             // Nw*100
    float* segA = BIG + (size_t)Nw * OUT_C;        // Nw*100
    float* wh1  = BIG + (size_t)2 * Nw * OUT_C;    // Nw*200
    float* segB = BIG;                             // Nw*200 (overlays wh0+segA, both dead)
    // phase E: h0/agg live inside d_out (zeroed afterwards, before final scatter)
    float* h0  = (float*)d_out;                    // N*200
    float* agg = (float*)d_out + (size_t)N * H_C;  // N*200 (layer1) / N*100 (layer2)
    float* h1  = BIG;                              // N*100 (segB/wh1 dead by then)
    float* Q   = BIG;                              // M*200 (h1 dead after gemm h2)

    // =============== phase W: word GCN ===============
    hipMemsetAsync(wcnt, 0, (size_t)Nw * 4, stream);
    hipMemsetAsync(ecnt, 0, (size_t)N * 4, stream);
    hipMemsetAsync(segA, 0, (size_t)Nw * OUT_C * 4, stream);

    gather_rows_k<OUT_C, false><<<ew_grid((size_t)Nw * OUT_C), 256, 0, stream>>>(
        word_embeds, word_id, wh0, Nw);
    count_k<<<ew_grid(Ew), 256, 0, stream>>>(wdst, wcnt, Ew);
    count_k<<<ew_grid(E), 256, 0, stream>>>(edge_dst, ecnt, E);
    inv_k<<<ew_grid(Nw), 256, 0, stream>>>(wcnt, Nw);
    inv_k<<<ew_grid(N), 256, 0, stream>>>(ecnt, N);

    scatter_add_k<OUT_C><<<ew_grid((size_t)Ew * OUT_C), 256, 0, stream>>>(
        wh0, wsrc, wdst, segA, Ew);
    // wh1 = relu(mean(segA) @ gcn_w1 + b1)   [30000 x 200]
    launch_gemm<1, false, false>(stream, segA, gcn_w1, wcnt, nullptr, nullptr, gcn_b1,
                                 wh1, nullptr, Nw, H_C, OUT_C);
    hipMemsetAsync(segB, 0, (size_t)Nw * H_C * 4, stream);
    scatter_add_k<H_C><<<ew_grid((size_t)Ew * H_C), 256, 0, stream>>>(
        wh1, wsrc, wdst, segB, Ew);
    // wh = relu(mean(segB) @ gcn_w2 + b2)   [30000 x 200]
    launch_gemm<1, false, false>(stream, segB, gcn_w2, wcnt, nullptr, nullptr, gcn_b2,
                                 wh, nullptr, Nw, H_C, H_C);

    // =============== phase E: CompGCN ===============
    gather_rows_k<H_C, true><<<ew_grid((size_t)N * H_C), 256, 0, stream>>>(
        ent_embeds, node_slot, h0, N);
    hipMemsetAsync(agg, 0, (size_t)N * H_C * 4, stream);
    scatter_add_sub_k<H_C><<<ew_grid((size_t)E * H_C), 256, 0, stream>>>(
        h0, rel_embeds, edge_src, edge_dst, edge_type, agg, E);
    // rel1 = rel_embeds @ cg1_wr   [240 x 100]
    launch_gemm<0, false, false>(stream, rel_embeds, cg1_wr, nullptr, nullptr, nullptr, nullptr,
                                 rel1, nullptr, NREL_C, OUT_C, H_C);
    // h1 = relu(mean(agg) @ cg1_wn + h0 @ cg1_wl)   [50000 x 100]
    launch_gemm<1, true, false>(stream, agg, cg1_wn, ecnt, h0, cg1_wl, nullptr,
                                h1, nullptr, N, OUT_C, H_C);
    hipMemsetAsync(agg, 0, (size_t)N * OUT_C * 4, stream);
    scatter_add_sub_k<OUT_C><<<ew_grid((size_t)E * OUT_C), 256, 0, stream>>>(
        h1, rel1, edge_src, edge_dst, edge_type, agg, E);
    // rel2 = rel1 @ cg2_wr   [240 x 200]
    launch_gemm<0, false, false>(stream, rel1, cg2_wr, nullptr, nullptr, nullptr, nullptr,
                                 rel2, nullptr, NREL_C, H_C, OUT_C);
    // h2 = relu(mean(agg) @ cg2_wn + h1 @ cg2_wl)   [50000 x 200]
    launch_gemm<1, true, false>(stream, agg, cg2_wn, ecnt, h1, cg2_wl, nullptr,
                                h2, nullptr, N, H_C, OUT_C);

    // =============== phase A: attention + output ===============
    hipMemsetAsync(d_out, 0, (size_t)out_size * 4, stream);  // h0/agg (in d_out) now dead
    build_q_k<<<ew_grid((size_t)M * H_C), 256, 0, stream>>>(
        h2, rel2, edge_type, r_ids_graph, Q, N, M);
    // QA = Q @ attn_wa   [58192 x 200]
    launch_gemm<0, false, false>(stream, Q, attn_wa, nullptr, nullptr, nullptr, nullptr,
                                 QA, nullptr, M, H_C, H_C);
    rowoff_k<<<ew_grid(M), 256, 0, stream>>>(node_slot, edge_slot, rowOff, N, M, divq, per, embBase);
    attn_k<<<(M + 3) / 4, 256, 0, stream>>>(QA, wh, ent_word_idx, ent_word_mask,
                                            rel_word_idx, rel_word_mask, N, M);
    // out = tanh(ctx @ wc[0:200] + Q @ wc[200:400]) scattered into d_out
    launch_gemm<2, true, true>(stream, QA, attn_wc, nullptr, Q, attn_wc + (size_t)H_C * H_C,
                               nullptr, (float*)d_out, rowOff, M, H_C, H_C);
}

// Round 2
// 1367.139 us; speedup vs baseline: 1.4467x; 1.4467x over previous
//
#include <hip/hip_runtime.h>
#include <cstddef>

// Problem constants (fixed by the reference)
constexpr int NUM_ENT_C = 10000;
constexpr int SEQ_C     = 10;
constexpr int H_C       = 200;   // hidden dim
constexpr int OUT_C     = 100;   // word-embed / mid dim
constexpr int NG_C      = 2048;
constexpr int NREL_C    = 240;
constexpr int MQ_C      = 8;

typedef __attribute__((ext_vector_type(8))) short    bf16x8;
typedef __attribute__((ext_vector_type(4))) float    f32x4;
typedef __attribute__((ext_vector_type(8))) unsigned short u16x8;

__device__ __forceinline__ unsigned short f2bf(float v) {
    unsigned u = __float_as_uint(v);
    unsigned r = (u + 0x7FFFu + ((u >> 16) & 1u)) >> 16;   // RTN-even
    return (unsigned short)r;
}

// ---------------------------------------------------------------------------
// Elementwise / gather / scatter kernels
// ---------------------------------------------------------------------------

template<int D, bool MOD>
__global__ void gather_rows_k(const float* __restrict__ src, const int* __restrict__ idx,
                              float* __restrict__ dst, int n) {
    size_t total  = (size_t)n * D;
    size_t stride = (size_t)gridDim.x * blockDim.x;
    for (size_t t = (size_t)blockIdx.x * blockDim.x + threadIdx.x; t < total; t += stride) {
        size_t i = t / D;
        int d = (int)(t - i * D);
        int r = idx[i];
        if (MOD) r = r % NUM_ENT_C;
        dst[t] = src[(size_t)r * D + d];
    }
}

__global__ void count_k(const int* __restrict__ dIdx, float* __restrict__ cnt, int E) {
    int stride = gridDim.x * blockDim.x;
    for (int t = blockIdx.x * blockDim.x + threadIdx.x; t < E; t += stride)
        atomicAdd(&cnt[dIdx[t]], 1.0f);
}

__global__ void inv_k(float* __restrict__ c, int n) {
    int stride = gridDim.x * blockDim.x;
    for (int t = blockIdx.x * blockDim.x + threadIdx.x; t < n; t += stride)
        c[t] = 1.0f / fmaxf(c[t], 1.0f);
}

template<int D>
__global__ void scatter_add_k(const float* __restrict__ feat, const int* __restrict__ sIdx,
                              const int* __restrict__ dIdx, float* __restrict__ out, int E) {
    size_t total  = (size_t)E * D;
    size_t stride = (size_t)gridDim.x * blockDim.x;
    for (size_t t = (size_t)blockIdx.x * blockDim.x + threadIdx.x; t < total; t += stride) {
        size_t e = t / D;
        int d = (int)(t - e * D);
        atomicAdd(&out[(size_t)dIdx[e] * D + d], feat[(size_t)sIdx[e] * D + d]);
    }
}

template<int D>
__global__ void scatter_add_sub_k(const float* __restrict__ hfeat, const float* __restrict__ rel,
                                  const int* __restrict__ sIdx, const int* __restrict__ dIdx,
                                  const int* __restrict__ tIdx, float* __restrict__ out, int E) {
    size_t total  = (size_t)E * D;
    size_t stride = (size_t)gridDim.x * blockDim.x;
    for (size_t t = (size_t)blockIdx.x * blockDim.x + threadIdx.x; t < total; t += stride) {
        size_t e = t / D;
        int d = (int)(t - e * D);
        float v = hfeat[(size_t)sIdx[e] * D + d] - rel[(size_t)tIdx[e] * D + d];
        atomicAdd(&out[(size_t)dIdx[e] * D + d], v);
    }
}

__global__ void build_q_k(const float* __restrict__ h2, const float* __restrict__ rel2,
                          const int* __restrict__ edge_type, const int* __restrict__ r_ids,
                          float* __restrict__ Q, int N, int M) {
    size_t total  = (size_t)M * H_C;
    size_t stride = (size_t)gridDim.x * blockDim.x;
    for (size_t t = (size_t)blockIdx.x * blockDim.x + threadIdx.x; t < total; t += stride) {
        size_t m = t / H_C;
        int d = (int)(t - m * H_C);
        if ((int)m < N) {
            Q[t] = h2[t];
        } else {
            int rr = r_ids[(int)m - N];
            Q[t] = rel2[(size_t)edge_type[rr] * H_C + d];
        }
    }
}

__global__ void rowoff_k(const int* __restrict__ node_slot, const int* __restrict__ edge_slot,
                         int* __restrict__ rowOff, int N, int M, int divq, int per, int embBase) {
    int stride = gridDim.x * blockDim.x;
    for (int m = blockIdx.x * blockDim.x + threadIdx.x; m < M; m += stride) {
        int off;
        if (m < N) {
            int ns = node_slot[m];
            int nid  = ns % NUM_ENT_C;
            int gidx = ns / divq;
            off = embBase + (nid * SEQ_C + gidx) * H_C;
        } else {
            int es  = edge_slot[m - N];
            int row = es / per;
            int pos = es - row * per;
            off = (row * SEQ_C + pos) * H_C;
        }
        rowOff[m] = off;
    }
}

// ---------------------------------------------------------------------------
// bf16 conversion kernels
// A: dst[M][Kp] = [A1*scale (K1) || A2 (K2) || 0-pad], bf16
// ---------------------------------------------------------------------------
__global__ void convA_k(const float* __restrict__ A1, const float* __restrict__ scale, int K1,
                        const float* __restrict__ A2, int K2,
                        unsigned short* __restrict__ dst, int M, int Kp) {
    int cpr = Kp >> 3;                 // 16B chunks per row
    size_t total  = (size_t)M * cpr;
    size_t stride = (size_t)gridDim.x * blockDim.x;
    for (size_t t = (size_t)blockIdx.x * blockDim.x + threadIdx.x; t < total; t += stride) {
        int m  = (int)(t / cpr);
        int kc = (int)(t - (size_t)m * cpr) << 3;
        float s = scale ? scale[m] : 1.0f;
        u16x8 o;
        #pragma unroll
        for (int i = 0; i < 8; ++i) {
            int k = kc + i;
            float v = 0.0f;
            if (k < K1)            v = A1[(size_t)m * K1 + k] * s;
            else if (k < K1 + K2)  v = A2[(size_t)m * K2 + (k - K1)];
            o[i] = f2bf(v);
        }
        *reinterpret_cast<u16x8*>(dst + (size_t)m * Kp + kc) = o;
    }
}

// W: dst[n][k] (n<Nt rows, zero-padded), sources row-major W1[K1][N], W2[K2][N]
__global__ void convW_k(const float* __restrict__ W1, int K1,
                        const float* __restrict__ W2, int K2, int N,
                        unsigned short* __restrict__ dst, int Nt, int Kp) {
    int total  = Nt * Kp;
    int stride = gridDim.x * blockDim.x;
    for (int t = blockIdx.x * blockDim.x + threadIdx.x; t < total; t += stride) {
        int n = t / Kp;
        int k = t - n * Kp;
        float v = 0.0f;
        if (n < N) {
            if (k < K1)           v = W1[(size_t)k * N + n];
            else if (k < K1 + K2) v = W2[(size_t)(k - K1) * N + n];
        }
        dst[t] = f2bf(v);
    }
}

// ---------------------------------------------------------------------------
// MFMA bf16 GEMM: C[M][N] = act(A[M][Kp] @ Wt[Nt][Kp]^T + bias), f32 out.
// Block: 64 rows x full N (NF 16-col fragments). 4 waves, wave w owns rows
// [16w,16w+16). One 16x16x32 MFMA per (nf, 32-k step).
// ---------------------------------------------------------------------------
template<int NF, int ACT, bool SCATTER>
__global__ __launch_bounds__(256) void mfma_gemm_k(
        const unsigned short* __restrict__ A, const unsigned short* __restrict__ Wt,
        const float* __restrict__ bias, float* __restrict__ C,
        const int* __restrict__ rowOff, int M, int N, int Kp) {
    constexpr int BN = NF * 16;
    __shared__ unsigned short As[64][40];   // 32 k + 8 pad (80B rows: conflict-free-ish)
    __shared__ unsigned short Bs[BN][40];
    const int tid  = threadIdx.x;
    const int bm   = blockIdx.x * 64;
    const int w    = tid >> 6;
    const int lane = tid & 63;
    const int lr   = lane & 15;        // A-row / B-col within fragment
    const int lk   = (lane >> 4) * 8;  // k offset within 32

    f32x4 acc[NF];
    #pragma unroll
    for (int nf = 0; nf < NF; ++nf) acc[nf] = (f32x4){0.f, 0.f, 0.f, 0.f};

    for (int k0 = 0; k0 < Kp; k0 += 32) {
        {   // stage A tile: 64 rows x 32 k, one 16B chunk per thread
            int m = tid >> 2, c = tid & 3;
            int gm = bm + m;
            uint4 v = make_uint4(0u, 0u, 0u, 0u);
            if (gm < M) v = *reinterpret_cast<const uint4*>(A + (size_t)gm * Kp + k0 + c * 8);
            *reinterpret_cast<uint4*>(&As[m][c * 8]) = v;
        }
        // stage B tile: BN rows x 32 k
        for (int i = tid; i < NF * 64; i += 256) {
            int n = i >> 2, c = i & 3;
            uint4 v = *reinterpret_cast<const uint4*>(Wt + (size_t)n * Kp + k0 + c * 8);
            *reinterpret_cast<uint4*>(&Bs[n][c * 8]) = v;
        }
        __syncthreads();
        bf16x8 a = *reinterpret_cast<const bf16x8*>(&As[w * 16 + lr][lk]);
        #pragma unroll
        for (int nf = 0; nf < NF; ++nf) {
            bf16x8 b = *reinterpret_cast<const bf16x8*>(&Bs[nf * 16 + lr][lk]);
            acc[nf] = __builtin_amdgcn_mfma_f32_16x16x32_bf16(a, b, acc[nf], 0, 0, 0);
        }
        __syncthreads();
    }

    // epilogue: D mapping col=lane&15, row=(lane>>4)*4+j (verified layout)
    const int r0 = (lane >> 4) * 4;
    #pragma unroll
    for (int j = 0; j < 4; ++j) {
        int gm = bm + w * 16 + r0 + j;
        if (gm >= M) continue;
        size_t base = SCATTER ? (size_t)rowOff[gm] : (size_t)gm * N;
        #pragma unroll
        for (int nf = 0; nf < NF; ++nf) {
            int gn = nf * 16 + lr;
            if (gn >= N) continue;
            float v = acc[nf][j];
            if (bias) v += bias[gn];
            if (ACT == 1) v = fmaxf(v, 0.f);
            if (ACT == 2) v = tanhf(v);
            C[base + gn] = v;
        }
    }
}

template<int NF, int ACT, bool SCATTER>
static void launch_mfma(hipStream_t s, const unsigned short* A, const unsigned short* Wt,
                        const float* bias, float* C, const int* rowOff, int M, int N, int Kp) {
    mfma_gemm_k<NF, ACT, SCATTER><<<dim3((M + 63) / 64), 256, 0, s>>>(A, Wt, bias, C, rowOff, M, N, Kp);
}

// ---------------------------------------------------------------------------
// Small f32 GEMM (for the 240-row rel transforms): C = A @ W
// ---------------------------------------------------------------------------
__global__ __launch_bounds__(256) void gemm_f32_k(
        const float* __restrict__ A, const float* __restrict__ W,
        float* __restrict__ C, int M, int N, int K) {
    constexpr int TS = 64, BK = 16;
    __shared__ float As[BK][TS];
    __shared__ float Bs[BK][TS];
    int bm = blockIdx.x * TS, bn = blockIdx.y * TS;
    int tid = threadIdx.x;
    int tx = tid & 15, ty = tid >> 4;
    float acc[4][4] = {};
    for (int k0 = 0; k0 < K; k0 += BK) {
        #pragma unroll
        for (int l = tid; l < TS * BK; l += 256) {
            int m = l >> 4, kk = l & 15;
            int gm = bm + m, gk = k0 + kk;
            As[kk][m] = (gm < M && gk < K) ? A[(size_t)gm * K + gk] : 0.f;
        }
        #pragma unroll
        for (int l = tid; l < TS * BK; l += 256) {
            int kk = l >> 6, n = l & 63;
            int gk = k0 + kk, gn = bn + n;
            Bs[kk][n] = (gk < K && gn < N) ? W[(size_t)gk * N + gn] : 0.f;
        }
        __syncthreads();
        #pragma unroll
        for (int kk = 0; kk < BK; ++kk) {
            float a[4], b[4];
            #pragma unroll
            for (int i = 0; i < 4; ++i) a[i] = As[kk][ty * 4 + i];
            #pragma unroll
            for (int j = 0; j < 4; ++j) b[j] = Bs[kk][tx * 4 + j];
            #pragma unroll
            for (int i = 0; i < 4; ++i)
                #pragma unroll
                for (int j = 0; j < 4; ++j) acc[i][j] += a[i] * b[j];
        }
        __syncthreads();
    }
    #pragma unroll
    for (int i = 0; i < 4; ++i) {
        int gm = bm + ty * 4 + i;
        if (gm >= M) continue;
        #pragma unroll
        for (int j = 0; j < 4; ++j) {
            int gn = bn + tx * 4 + j;
            if (gn < N) C[(size_t)gm * N + gn] = acc[i][j];
        }
    }
}

// ---------------------------------------------------------------------------
// Attention: one wave per row m
// ---------------------------------------------------------------------------
__global__ __launch_bounds__(256) void attn_k(
        float* __restrict__ QActx, const float* __restrict__ wh,
        const int* __restrict__ ent_idx, const int* __restrict__ ent_mask,
        const int* __restrict__ rel_idx, const int* __restrict__ rel_mask,
        int N, int M) {
    int wave = (int)(((size_t)blockIdx.x * blockDim.x + threadIdx.x) >> 6);
    int lane = threadIdx.x & 63;
    if (wave >= M) return;
    int m = wave;
    const int* idxp;
    const int* mskp;
    if (m < N) { idxp = ent_idx + (size_t)m * MQ_C;        mskp = ent_mask + (size_t)m * MQ_C; }
    else       { idxp = rel_idx + (size_t)(m - N) * MQ_C;  mskp = rel_mask + (size_t)(m - N) * MQ_C; }

    float qa[4];
    #pragma unroll
    for (int j = 0; j < 4; ++j) {
        int d = j * 64 + lane;
        qa[j] = (d < H_C) ? QActx[(size_t)m * H_C + d] : 0.f;
    }
    int   idx[MQ_C];
    float msk[MQ_C];
    float s[MQ_C];
    #pragma unroll
    for (int k = 0; k < MQ_C; ++k) { idx[k] = idxp[k]; msk[k] = (float)mskp[k]; }
    #pragma unroll
    for (int k = 0; k < MQ_C; ++k) {
        const float* w = wh + (size_t)idx[k] * H_C;
        float p = 0.f;
        #pragma unroll
        for (int j = 0; j < 4; ++j) {
            int d = j * 64 + lane;
            if (d < H_C) p += qa[j] * w[d];
        }
        #pragma unroll
        for (int off = 32; off; off >>= 1) p += __shfl_xor(p, off);
        s[k] = p * msk[k];
    }
    float mx = s[0];
    #pragma unroll
    for (int k = 1; k < MQ_C; ++k) mx = fmaxf(mx, s[k]);
    float den = 0.f;
    #pragma unroll
    for (int k = 0; k < MQ_C; ++k) { s[k] = expf(s[k] - mx); den += s[k]; }
    float inv = 1.f / den;
    #pragma unroll
    for (int j = 0; j < 4; ++j) {
        int d = j * 64 + lane;
        if (d >= H_C) continue;
        float c = 0.f;
        #pragma unroll
        for (int k = 0; k < MQ_C; ++k) c += s[k] * msk[k] * wh[(size_t)idx[k] * H_C + d];
        QActx[(size_t)m * H_C + d] = c * inv;
    }
}

// ---------------------------------------------------------------------------

static inline dim3 ew_grid(size_t total) {
    size_t b = (total + 255) / 256;
    if (b > 4096) b = 4096;
    return dim3((unsigned)b);
}
static inline int kpad(int k) { return (k + 31) & ~31; }

extern "C" void kernel_launch(void* const* d_in, const int* in_sizes, int n_in,
                              void* d_out, int out_size, void* d_ws, size_t ws_size,
                              hipStream_t stream) {
    const float* ent_embeds = (const float*)d_in[0];
    const float* rel_embeds = (const float*)d_in[1];
    const float* word_embeds= (const float*)d_in[2];
    const float* gcn_w1     = (const float*)d_in[3];
    const float* gcn_b1     = (const float*)d_in[4];
    const float* gcn_w2     = (const float*)d_in[5];
    const float* gcn_b2     = (const float*)d_in[6];
    const float* cg1_wn     = (const float*)d_in[7];
    const float* cg1_wl     = (const float*)d_in[8];
    const float* cg1_wr     = (const float*)d_in[9];
    const float* cg2_wn     = (const float*)d_in[10];
    const float* cg2_wl     = (const float*)d_in[11];
    const float* cg2_wr     = (const float*)d_in[12];
    const float* attn_wa    = (const float*)d_in[13];
    const float* attn_wc    = (const float*)d_in[14];
    const int* node_slot    = (const int*)d_in[15];
    const int* edge_src     = (const int*)d_in[16];
    const int* edge_dst     = (const int*)d_in[17];
    const int* edge_type    = (const int*)d_in[18];
    const int* word_id      = (const int*)d_in[19];
    const int* wsrc         = (const int*)d_in[20];
    const int* wdst         = (const int*)d_in[21];
    const int* ent_word_idx = (const int*)d_in[22];
    const int* ent_word_mask= (const int*)d_in[23];
    const int* rel_word_idx = (const int*)d_in[24];
    const int* rel_word_mask= (const int*)d_in[25];
    const int* r_ids_graph  = (const int*)d_in[26];
    const int* edge_slot    = (const int*)d_in[27];

    const int N    = in_sizes[15];          // 50000
    const int E    = in_sizes[16];          // 200000
    const int Nw   = in_sizes[19];          // 30000
    const int Ew   = in_sizes[20];          // 300000
    const int Rsel = in_sizes[27];          // 8192
    const int M    = N + Rsel;              // 58192
    const int divq = N / SEQ_C;
    const int per  = Rsel / NG_C;
    const int embBase = NG_C * SEQ_C * H_C;

    // ---- workspace carving (floats)
    float* ws = (float*)d_ws;
    size_t o = 0;
    float* wcnt = ws + o; o += Nw;
    float* ecnt = ws + o; o += N;
    float* rel1 = ws + o; o += (size_t)NREL_C * OUT_C;
    float* rel2 = ws + o; o += (size_t)NREL_C * H_C;
    int*   rowOff = (int*)(ws + o); o += M;  // 58192 (keeps 16B alignment: 210192 % 4 == 0)
    unsigned short* Wt = (unsigned short*)(ws + o); o += 47104;  // up to 208x448 bf16
    float* wh   = ws + o; o += (size_t)Nw * H_C;   // 6M,  persists
    float* h2   = ws + o; o += (size_t)N * H_C;    // 10M, persists
    float* R    = ws + o;                          // 24.2M phase-local region

    // phase-local views in R
    float* wh0  = R;                                   // 3M
    float* segA = R + (size_t)Nw * OUT_C;              // 3M
    float* wh1  = R + (size_t)2 * Nw * OUT_C;          // @6M, 6M
    float* segB = R;                                   // 6M (over wh0+segA)
    unsigned short* AbfW = (unsigned short*)(R + 12000000);  // phase W conv buf
    float* h1   = R;                                   // 5M (phase E)
    unsigned short* AbfE = (unsigned short*)(R + 6000000);   // phase E conv buf (10.4M fl)
    float* Q    = R;                                   // 11.64M (phase A)
    unsigned short* AbfA = (unsigned short*)(R + 12000000);  // phase A conv buf (12.1M fl)
    // h0 / agg / QA live inside d_out (zeroed before the final scatter)
    float* h0  = (float*)d_out;                    // N*200
    float* agg = (float*)d_out + (size_t)N * H_C;  // N*200 / N*100
    float* QA  = (float*)d_out;                    // M*200 (phase A)

    // =============== phase W: word GCN ===============
    hipMemsetAsync(wcnt, 0, (size_t)Nw * 4, stream);
    hipMemsetAsync(ecnt, 0, (size_t)N * 4, stream);
    hipMemsetAsync(segA, 0, (size_t)Nw * OUT_C * 4, stream);

    gather_rows_k<OUT_C, false><<<ew_grid((size_t)Nw * OUT_C), 256, 0, stream>>>(
        word_embeds, word_id, wh0, Nw);
    count_k<<<ew_grid(Ew), 256, 0, stream>>>(wdst, wcnt, Ew);
    count_k<<<ew_grid(E), 256, 0, stream>>>(edge_dst, ecnt, E);
    inv_k<<<ew_grid(Nw), 256, 0, stream>>>(wcnt, Nw);
    inv_k<<<ew_grid(N), 256, 0, stream>>>(ecnt, N);

    scatter_add_k<OUT_C><<<ew_grid((size_t)Ew * OUT_C), 256, 0, stream>>>(
        wh0, wsrc, wdst, segA, Ew);
    // wh1 = relu(mean(segA) @ gcn_w1 + b1)   [30000 x 200], K=100->128
    {
        int Kp = kpad(OUT_C);
        convW_k<<<ew_grid(208 * Kp), 256, 0, stream>>>(gcn_w1, OUT_C, nullptr, 0, H_C, Wt, 208, Kp);
        convA_k<<<ew_grid((size_t)Nw * Kp / 8), 256, 0, stream>>>(segA, wcnt, OUT_C, nullptr, 0, AbfW, Nw, Kp);
        launch_mfma<13, 1, false>(stream, AbfW, Wt, gcn_b1, wh1, nullptr, Nw, H_C, Kp);
    }
    hipMemsetAsync(segB, 0, (size_t)Nw * H_C * 4, stream);
    scatter_add_k<H_C><<<ew_grid((size_t)Ew * H_C), 256, 0, stream>>>(
        wh1, wsrc, wdst, segB, Ew);
    // wh = relu(mean(segB) @ gcn_w2 + b2)   [30000 x 200], K=200->224
    {
        int Kp = kpad(H_C);
        convW_k<<<ew_grid(208 * Kp), 256, 0, stream>>>(gcn_w2, H_C, nullptr, 0, H_C, Wt, 208, Kp);
        convA_k<<<ew_grid((size_t)Nw * Kp / 8), 256, 0, stream>>>(segB, wcnt, H_C, nullptr, 0, AbfW, Nw, Kp);
        launch_mfma<13, 1, false>(stream, AbfW, Wt, gcn_b2, wh, nullptr, Nw, H_C, Kp);
    }

    // =============== phase E: CompGCN ===============
    gather_rows_k<H_C, true><<<ew_grid((size_t)N * H_C), 256, 0, stream>>>(
        ent_embeds, node_slot, h0, N);
    hipMemsetAsync(agg, 0, (size_t)N * H_C * 4, stream);
    scatter_add_sub_k<H_C><<<ew_grid((size_t)E * H_C), 256, 0, stream>>>(
        h0, rel_embeds, edge_src, edge_dst, edge_type, agg, E);
    gemm_f32_k<<<dim3((NREL_C + 63) / 64, (OUT_C + 63) / 64), 256, 0, stream>>>(
        rel_embeds, cg1_wr, rel1, NREL_C, OUT_C, H_C);
    // h1 = relu([mean(agg)||h0] @ [wn;wl])   [50000 x 100], K=400->416
    {
        int Kp = kpad(2 * H_C);
        convW_k<<<ew_grid(112 * Kp), 256, 0, stream>>>(cg1_wn, H_C, cg1_wl, H_C, OUT_C, Wt, 112, Kp);
        convA_k<<<ew_grid((size_t)N * Kp / 8), 256, 0, stream>>>(agg, ecnt, H_C, h0, H_C, AbfE, N, Kp);
        launch_mfma<7, 1, false>(stream, AbfE, Wt, nullptr, h1, nullptr, N, OUT_C, Kp);
    }
    hipMemsetAsync(agg, 0, (size_t)N * OUT_C * 4, stream);
    scatter_add_sub_k<OUT_C><<<ew_grid((size_t)E * OUT_C), 256, 0, stream>>>(
        h1, rel1, edge_src, edge_dst, edge_type, agg, E);
    gemm_f32_k<<<dim3((NREL_C + 63) / 64, (H_C + 63) / 64), 256, 0, stream>>>(
        rel1, cg2_wr, rel2, NREL_C, H_C, OUT_C);
    // h2 = relu([mean(agg)||h1] @ [wn;wl])   [50000 x 200], K=200->224
    {
        int Kp = kpad(2 * OUT_C);
        convW_k<<<ew_grid(208 * Kp), 256, 0, stream>>>(cg2_wn, OUT_C, cg2_wl, OUT_C, H_C, Wt, 208, Kp);
        convA_k<<<ew_grid((size_t)N * Kp / 8), 256, 0, stream>>>(agg, ecnt, OUT_C, h1, OUT_C, AbfE, N, Kp);
        launch_mfma<13, 1, false>(stream, AbfE, Wt, nullptr, h2, nullptr, N, H_C, Kp);
    }

    // =============== phase A: attention + output ===============
    build_q_k<<<ew_grid((size_t)M * H_C), 256, 0, stream>>>(
        h2, rel2, edge_type, r_ids_graph, Q, N, M);
    // QA = Q @ attn_wa   [58192 x 200], K=200->224 (QA lives in d_out)
    {
        int Kp = kpad(H_C);
        convW_k<<<ew_grid(208 * Kp), 256, 0, stream>>>(attn_wa, H_C, nullptr, 0, H_C, Wt, 208, Kp);
        convA_k<<<ew_grid((size_t)M * Kp / 8), 256, 0, stream>>>(Q, nullptr, H_C, nullptr, 0, AbfA, M, Kp);
        launch_mfma<13, 0, false>(stream, AbfA, Wt, nullptr, QA, nullptr, M, H_C, Kp);
    }
    rowoff_k<<<ew_grid(M), 256, 0, stream>>>(node_slot, edge_slot, rowOff, N, M, divq, per, embBase);
    attn_k<<<(M + 3) / 4, 256, 0, stream>>>(QA, wh, ent_word_idx, ent_word_mask,
                                            rel_word_idx, rel_word_mask, N, M);
    // out = tanh([ctx||Q] @ attn_wc) scattered into d_out, K=400->416
    {
        int Kp = kpad(4 * OUT_C);
        convW_k<<<ew_grid(208 * Kp), 256, 0, stream>>>(attn_wc, H_C, attn_wc + (size_t)H_C * H_C, H_C,
                                                       H_C, Wt, 208, Kp);
        convA_k<<<ew_grid((size_t)M * Kp / 8), 256, 0, stream>>>(QA, nullptr, H_C, Q, H_C, AbfA, M, Kp);
        hipMemsetAsync(d_out, 0, (size_t)out_size * 4, stream);
        launch_mfma<13, 2, true>(stream, AbfA, Wt, nullptr, (float*)d_out, rowOff, M, H_C, Kp);
    }
}

// Round 3
// 830.499 us; speedup vs baseline: 2.3815x; 1.6462x over previous
//
#include <hip/hip_runtime.h>
#include <cstddef>

// Problem constants (fixed by the reference)
constexpr int NUM_ENT_C = 10000;
constexpr int SEQ_C     = 10;
constexpr int H_C       = 200;   // hidden dim
constexpr int OUT_C     = 100;   // word-embed / mid dim
constexpr int NG_C      = 2048;
constexpr int NREL_C    = 240;
constexpr int MQ_C      = 8;

typedef __attribute__((ext_vector_type(8))) short          bf16x8;
typedef __attribute__((ext_vector_type(4))) float          f32x4;
typedef __attribute__((ext_vector_type(8))) unsigned short u16x8;

__device__ __forceinline__ unsigned short f2bf(float v) {
    unsigned u = __float_as_uint(v);
    unsigned r = (u + 0x7FFFu + ((u >> 16) & 1u)) >> 16;   // RTN-even
    return (unsigned short)r;
}

// ---------------------------------------------------------------------------
// CSR build: histogram -> block scan -> bucket fill
// ---------------------------------------------------------------------------
__global__ void hist_k(const int* __restrict__ dIdx, int* __restrict__ deg, int E) {
    int stride = gridDim.x * blockDim.x;
    for (int t = blockIdx.x * blockDim.x + threadIdx.x; t < E; t += stride)
        atomicAdd(&deg[dIdx[t]], 1);
}

__global__ void scanA_k(const int* __restrict__ v, int* __restrict__ bsum, int n) {
    __shared__ int s[256];
    int t = threadIdx.x;
    int i = blockIdx.x * 256 + t;
    s[t] = (i < n) ? v[i] : 0;
    __syncthreads();
    for (int d = 128; d; d >>= 1) {
        if (t < d) s[t] += s[t + d];
        __syncthreads();
    }
    if (t == 0) bsum[blockIdx.x] = s[0];
}

// nb <= 256 (holds: max 196 blocks)
__global__ void scanB_k(int* __restrict__ bsum, int nb) {
    __shared__ int s[256];
    int t = threadIdx.x;
    int v = (t < nb) ? bsum[t] : 0;
    s[t] = v;
    __syncthreads();
    for (int d = 1; d < 256; d <<= 1) {
        int x = (t >= d) ? s[t - d] : 0;
        __syncthreads();
        s[t] += x;
        __syncthreads();
    }
    if (t < nb) bsum[t] = s[t] - v;   // exclusive
}

__global__ void scanC_k(const int* __restrict__ v, const int* __restrict__ bsum,
                        int* __restrict__ offs, int* __restrict__ cur, int n) {
    __shared__ int s[256];
    int t = threadIdx.x;
    int i = blockIdx.x * 256 + t;
    int val = (i < n) ? v[i] : 0;
    s[t] = val;
    __syncthreads();
    for (int d = 1; d < 256; d <<= 1) {
        int x = (t >= d) ? s[t - d] : 0;
        __syncthreads();
        s[t] += x;
        __syncthreads();
    }
    if (i < n) {
        int ex = s[t] - val + bsum[blockIdx.x];
        offs[i] = ex;
        cur[i]  = ex;
    }
}

__global__ void fill_k(const int* __restrict__ dIdx, int* __restrict__ cur,
                       int* __restrict__ bkt, int E) {
    int stride = gridDim.x * blockDim.x;
    for (int t = blockIdx.x * blockDim.x + threadIdx.x; t < E; t += stride) {
        int d = dIdx[t];
        int p = atomicAdd(&cur[d], 1);
        bkt[p] = t;
    }
}

// ---------------------------------------------------------------------------
// Gather-mean (+ optional rel-subtract) + self-append + bf16 row write.
// One wave per destination node. Output row: [mean(K1) || self(K2) || 0-pad]
// SRCMODE: 0 direct, 1 word_id[src], 2 src % NUM_ENT
// ---------------------------------------------------------------------------
template<int K1, int K2, int Kp, int SRCMODE, bool RELSUB, bool SELFMOD>
__global__ __launch_bounds__(256) void gather_mean_k(
        const float* __restrict__ feat, const float* __restrict__ selfFeat,
        const float* __restrict__ rel,
        const int* __restrict__ srcIdx, const int* __restrict__ typeIdx,
        const int* __restrict__ wordId,
        const int* __restrict__ offs, const int* __restrict__ deg,
        const int* __restrict__ bkt,
        unsigned short* __restrict__ dst, int n) {
    constexpr int NCH = (Kp + 63) / 64;
    int node = blockIdx.x * 4 + (threadIdx.x >> 6);
    int lane = threadIdx.x & 63;
    if (node >= n) return;
    float acc[NCH];
    #pragma unroll
    for (int c = 0; c < NCH; ++c) acc[c] = 0.f;
    int off = offs[node], dg = deg[node];
    for (int i = 0; i < dg; ++i) {
        int e = bkt[off + i];
        int s = srcIdx[e];
        if (SRCMODE == 1) s = wordId[s];
        if (SRCMODE == 2) s = s % NUM_ENT_C;
        const float* fr = feat + (size_t)s * K1;
        const float* rr = RELSUB ? rel + (size_t)typeIdx[e] * K1 : nullptr;
        #pragma unroll
        for (int c = 0; c < NCH; ++c) {
            int col = c * 64 + lane;
            if (col < K1) {
                float v = fr[col];
                if (RELSUB) v -= rr[col];
                acc[c] += v;
            }
        }
    }
    float inv = 1.f / fmaxf((float)dg, 1.f);
    int srow = SELFMOD ? (node % NUM_ENT_C) : node;
    unsigned short* drow = dst + (size_t)node * Kp;
    #pragma unroll
    for (int c = 0; c < NCH; ++c) {
        int col = c * 64 + lane;
        if (col >= Kp) continue;
        float v;
        if (col < K1)            v = acc[c] * inv;
        else if (col < K1 + K2)  v = selfFeat[(size_t)srow * K2 + (col - K1)];
        else                     v = 0.f;
        drow[col] = f2bf(v);
    }
}

// ---------------------------------------------------------------------------
// Weight conversion: dst[n][k] bf16 = [W1(K1) ; W2(K2)] column n, zero-padded
// ---------------------------------------------------------------------------
__global__ void convW_k(const float* __restrict__ W1, int K1,
                        const float* __restrict__ W2, int K2, int N,
                        unsigned short* __restrict__ dst, int Nt, int Kp) {
    int total  = Nt * Kp;
    int stride = gridDim.x * blockDim.x;
    for (int t = blockIdx.x * blockDim.x + threadIdx.x; t < total; t += stride) {
        int n = t / Kp;
        int k = t - n * Kp;
        float v = 0.0f;
        if (n < N) {
            if (k < K1)           v = W1[(size_t)k * N + n];
            else if (k < K1 + K2) v = W2[(size_t)(k - K1) * N + n];
        }
        dst[t] = f2bf(v);
    }
}

// rows N..M of the final concat matrix: cols 200..400 = rel2[edge_type[r_ids[r]]]
__global__ void build_q_bf16_k(const float* __restrict__ rel2, const int* __restrict__ edge_type,
                               const int* __restrict__ r_ids, unsigned short* __restrict__ A,
                               int N, int M) {
    int R = M - N;
    size_t total  = (size_t)R * H_C;
    size_t stride = (size_t)gridDim.x * blockDim.x;
    for (size_t t = (size_t)blockIdx.x * blockDim.x + threadIdx.x; t < total; t += stride) {
        int r = (int)(t / H_C);
        int d = (int)(t - (size_t)r * H_C);
        int rr = r_ids[r];
        A[(size_t)(N + r) * 448 + 200 + d] = f2bf(rel2[(size_t)edge_type[rr] * H_C + d]);
    }
}

// zero cols [400,448) of every 448-wide row
__global__ void zero_pad_k(unsigned short* __restrict__ A, int M) {
    int total  = M * 6;
    int stride = gridDim.x * blockDim.x;
    for (int t = blockIdx.x * blockDim.x + threadIdx.x; t < total; t += stride) {
        int m = t / 6, c = t - m * 6;
        *reinterpret_cast<uint4*>(A + (size_t)m * 448 + 400 + c * 8) = make_uint4(0u, 0u, 0u, 0u);
    }
}

__global__ void rowoff_k(const int* __restrict__ node_slot, const int* __restrict__ edge_slot,
                         int* __restrict__ rowOff, int N, int M, int divq, int per, int embBase) {
    int stride = gridDim.x * blockDim.x;
    for (int m = blockIdx.x * blockDim.x + threadIdx.x; m < M; m += stride) {
        int off;
        if (m < N) {
            int ns = node_slot[m];
            int nid  = ns % NUM_ENT_C;
            int gidx = ns / divq;
            off = embBase + (nid * SEQ_C + gidx) * H_C;
        } else {
            int es  = edge_slot[m - N];
            int row = es / per;
            int pos = es - row * per;
            off = (row * SEQ_C + pos) * H_C;
        }
        rowOff[m] = off;
    }
}

// ---------------------------------------------------------------------------
// MFMA bf16 GEMM: C = act(A[M][Kp](lda) @ Wt[Nt][Kp]^T + bias)
// OBF16: write bf16 at C[gm*ldc+gn]; else f32 (SCATTER: base=rowOff[gm])
// ---------------------------------------------------------------------------
template<int NF, int ACT, bool SCATTER, bool OBF16>
__global__ __launch_bounds__(256) void mfma_gemm_k(
        const unsigned short* __restrict__ A, int lda,
        const unsigned short* __restrict__ Wt,
        const float* __restrict__ bias, void* __restrict__ Cv, int ldc,
        const int* __restrict__ rowOff, int M, int N, int Kp) {
    constexpr int BN = NF * 16;
    __shared__ unsigned short As[64][40];
    __shared__ unsigned short Bs[BN][40];
    const int tid  = threadIdx.x;
    const int bm   = blockIdx.x * 64;
    const int w    = tid >> 6;
    const int lane = tid & 63;
    const int lr   = lane & 15;
    const int lk   = (lane >> 4) * 8;

    f32x4 acc[NF];
    #pragma unroll
    for (int nf = 0; nf < NF; ++nf) acc[nf] = (f32x4){0.f, 0.f, 0.f, 0.f};

    for (int k0 = 0; k0 < Kp; k0 += 32) {
        {
            int m = tid >> 2, c = tid & 3;
            int gm = bm + m;
            uint4 v = make_uint4(0u, 0u, 0u, 0u);
            if (gm < M) v = *reinterpret_cast<const uint4*>(A + (size_t)gm * lda + k0 + c * 8);
            *reinterpret_cast<uint4*>(&As[m][c * 8]) = v;
        }
        for (int i = tid; i < NF * 64; i += 256) {
            int n = i >> 2, c = i & 3;
            uint4 v = *reinterpret_cast<const uint4*>(Wt + (size_t)n * Kp + k0 + c * 8);
            *reinterpret_cast<uint4*>(&Bs[n][c * 8]) = v;
        }
        __syncthreads();
        bf16x8 a = *reinterpret_cast<const bf16x8*>(&As[w * 16 + lr][lk]);
        #pragma unroll
        for (int nf = 0; nf < NF; ++nf) {
            bf16x8 b = *reinterpret_cast<const bf16x8*>(&Bs[nf * 16 + lr][lk]);
            acc[nf] = __builtin_amdgcn_mfma_f32_16x16x32_bf16(a, b, acc[nf], 0, 0, 0);
        }
        __syncthreads();
    }

    const int r0 = (lane >> 4) * 4;
    #pragma unroll
    for (int j = 0; j < 4; ++j) {
        int gm = bm + w * 16 + r0 + j;
        if (gm >= M) continue;
        size_t base;
        if (OBF16)        base = (size_t)gm * ldc;
        else if (SCATTER) base = (size_t)rowOff[gm];
        else              base = (size_t)gm * ldc;
        #pragma unroll
        for (int nf = 0; nf < NF; ++nf) {
            int gn = nf * 16 + lr;
            if (gn >= N) continue;
            float v = acc[nf][j];
            if (bias) v += bias[gn];
            if (ACT == 1) v = fmaxf(v, 0.f);
            if (ACT == 2) v = tanhf(v);
            if (OBF16) ((unsigned short*)Cv)[base + gn] = f2bf(v);
            else       ((float*)Cv)[base + gn] = v;
        }
    }
}

template<int NF, int ACT, bool SCATTER, bool OBF16>
static void launch_mfma(hipStream_t s, const unsigned short* A, int lda,
                        const unsigned short* Wt, const float* bias,
                        void* C, int ldc, const int* rowOff, int M, int N, int Kp) {
    mfma_gemm_k<NF, ACT, SCATTER, OBF16><<<dim3((M + 63) / 64), 256, 0, s>>>(
        A, lda, Wt, bias, C, ldc, rowOff, M, N, Kp);
}

// ---------------------------------------------------------------------------
// Small f32 GEMM (240-row rel transforms)
// ---------------------------------------------------------------------------
__global__ __launch_bounds__(256) void gemm_f32_k(
        const float* __restrict__ A, const float* __restrict__ W,
        float* __restrict__ C, int M, int N, int K) {
    constexpr int TS = 64, BK = 16;
    __shared__ float As[BK][TS];
    __shared__ float Bs[BK][TS];
    int bm = blockIdx.x * TS, bn = blockIdx.y * TS;
    int tid = threadIdx.x;
    int tx = tid & 15, ty = tid >> 4;
    float acc[4][4] = {};
    for (int k0 = 0; k0 < K; k0 += BK) {
        #pragma unroll
        for (int l = tid; l < TS * BK; l += 256) {
            int m = l >> 4, kk = l & 15;
            int gm = bm + m, gk = k0 + kk;
            As[kk][m] = (gm < M && gk < K) ? A[(size_t)gm * K + gk] : 0.f;
        }
        #pragma unroll
        for (int l = tid; l < TS * BK; l += 256) {
            int kk = l >> 6, n = l & 63;
            int gk = k0 + kk, gn = bn + n;
            Bs[kk][n] = (gk < K && gn < N) ? W[(size_t)gk * N + gn] : 0.f;
        }
        __syncthreads();
        #pragma unroll
        for (int kk = 0; kk < BK; ++kk) {
            float a[4], b[4];
            #pragma unroll
            for (int i = 0; i < 4; ++i) a[i] = As[kk][ty * 4 + i];
            #pragma unroll
            for (int j = 0; j < 4; ++j) b[j] = Bs[kk][tx * 4 + j];
            #pragma unroll
            for (int i = 0; i < 4; ++i)
                #pragma unroll
                for (int j = 0; j < 4; ++j) acc[i][j] += a[i] * b[j];
        }
        __syncthreads();
    }
    #pragma unroll
    for (int i = 0; i < 4; ++i) {
        int gm = bm + ty * 4 + i;
        if (gm >= M) continue;
        #pragma unroll
        for (int j = 0; j < 4; ++j) {
            int gn = bn + tx * 4 + j;
            if (gn < N) C[(size_t)gm * N + gn] = acc[i][j];
        }
    }
}

// ---------------------------------------------------------------------------
// Attention: one wave per row; reads QA f32, writes ctx bf16 into concat matrix
// ---------------------------------------------------------------------------
__global__ __launch_bounds__(256) void attn_k(
        const float* __restrict__ QA, const float* __restrict__ wh,
        const int* __restrict__ ent_idx, const int* __restrict__ ent_mask,
        const int* __restrict__ rel_idx, const int* __restrict__ rel_mask,
        unsigned short* __restrict__ ctxOut, int N, int M) {
    int wave = (int)(((size_t)blockIdx.x * blockDim.x + threadIdx.x) >> 6);
    int lane = threadIdx.x & 63;
    if (wave >= M) return;
    int m = wave;
    const int* idxp;
    const int* mskp;
    if (m < N) { idxp = ent_idx + (size_t)m * MQ_C;        mskp = ent_mask + (size_t)m * MQ_C; }
    else       { idxp = rel_idx + (size_t)(m - N) * MQ_C;  mskp = rel_mask + (size_t)(m - N) * MQ_C; }

    float qa[4];
    #pragma unroll
    for (int j = 0; j < 4; ++j) {
        int d = j * 64 + lane;
        qa[j] = (d < H_C) ? QA[(size_t)m * H_C + d] : 0.f;
    }
    int   idx[MQ_C];
    float msk[MQ_C];
    float s[MQ_C];
    #pragma unroll
    for (int k = 0; k < MQ_C; ++k) { idx[k] = idxp[k]; msk[k] = (float)mskp[k]; }
    #pragma unroll
    for (int k = 0; k < MQ_C; ++k) {
        const float* w = wh + (size_t)idx[k] * H_C;
        float p = 0.f;
        #pragma unroll
        for (int j = 0; j < 4; ++j) {
            int d = j * 64 + lane;
            if (d < H_C) p += qa[j] * w[d];
        }
        #pragma unroll
        for (int off = 32; off; off >>= 1) p += __shfl_xor(p, off);
        s[k] = p * msk[k];
    }
    float mx = s[0];
    #pragma unroll
    for (int k = 1; k < MQ_C; ++k) mx = fmaxf(mx, s[k]);
    float den = 0.f;
    #pragma unroll
    for (int k = 0; k < MQ_C; ++k) { s[k] = expf(s[k] - mx); den += s[k]; }
    float inv = 1.f / den;
    #pragma unroll
    for (int j = 0; j < 4; ++j) {
        int d = j * 64 + lane;
        if (d >= H_C) continue;
        float c = 0.f;
        #pragma unroll
        for (int k = 0; k < MQ_C; ++k) c += s[k] * msk[k] * wh[(size_t)idx[k] * H_C + d];
        ctxOut[(size_t)m * 448 + d] = f2bf(c * inv);
    }
}

// ---------------------------------------------------------------------------

static inline dim3 ew_grid(size_t total) {
    size_t b = (total + 255) / 256;
    if (b > 4096) b = 4096;
    return dim3((unsigned)b);
}

extern "C" void kernel_launch(void* const* d_in, const int* in_sizes, int n_in,
                              void* d_out, int out_size, void* d_ws, size_t ws_size,
                              hipStream_t stream) {
    const float* ent_embeds = (const float*)d_in[0];
    const float* rel_embeds = (const float*)d_in[1];
    const float* word_embeds= (const float*)d_in[2];
    const float* gcn_w1     = (const float*)d_in[3];
    const float* gcn_b1     = (const float*)d_in[4];
    const float* gcn_w2     = (const float*)d_in[5];
    const float* gcn_b2     = (const float*)d_in[6];
    const float* cg1_wn     = (const float*)d_in[7];
    const float* cg1_wl     = (const float*)d_in[8];
    const float* cg1_wr     = (const float*)d_in[9];
    const float* cg2_wn     = (const float*)d_in[10];
    const float* cg2_wl     = (const float*)d_in[11];
    const float* cg2_wr     = (const float*)d_in[12];
    const float* attn_wa    = (const float*)d_in[13];
    const float* attn_wc    = (const float*)d_in[14];
    const int* node_slot    = (const int*)d_in[15];
    const int* edge_src     = (const int*)d_in[16];
    const int* edge_dst     = (const int*)d_in[17];
    const int* edge_type    = (const int*)d_in[18];
    const int* word_id      = (const int*)d_in[19];
    const int* wsrc         = (const int*)d_in[20];
    const int* wdst         = (const int*)d_in[21];
    const int* ent_word_idx = (const int*)d_in[22];
    const int* ent_word_mask= (const int*)d_in[23];
    const int* rel_word_idx = (const int*)d_in[24];
    const int* rel_word_mask= (const int*)d_in[25];
    const int* r_ids_graph  = (const int*)d_in[26];
    const int* edge_slot    = (const int*)d_in[27];

    const int N    = in_sizes[15];          // 50000
    const int E    = in_sizes[16];          // 200000
    const int Nw   = in_sizes[19];          // 30000
    const int Ew   = in_sizes[20];          // 300000
    const int Rsel = in_sizes[27];          // 8192
    const int M    = N + Rsel;              // 58192
    const int divq = N / SEQ_C;
    const int per  = Rsel / NG_C;
    const int embBase = NG_C * SEQ_C * H_C;

    // ---- workspace carving
    float* ws = (float*)d_ws;
    size_t o = 0;
    int* wdeg  = (int*)(ws + o); o += Nw;
    int* woffs = (int*)(ws + o); o += Nw;
    int* wcur  = (int*)(ws + o); o += Nw;
    int* edeg  = (int*)(ws + o); o += N;
    int* eoffs = (int*)(ws + o); o += N;
    int* ecur  = (int*)(ws + o); o += N;
    int* wbkt  = (int*)(ws + o); o += Ew;
    int* ebkt  = (int*)(ws + o); o += E;
    int* bsum  = (int*)(ws + o); o += 256;
    int* rowOff= (int*)(ws + o); o += M;
    float* rel1 = ws + o; o += (size_t)NREL_C * OUT_C;
    float* rel2 = ws + o; o += (size_t)NREL_C * H_C;
    o = (o + 3) & ~(size_t)3;                         // 16B align
    unsigned short* Wt = (unsigned short*)(ws + o); o += (208 * 448) / 2;
    float* wh = ws + o; o += (size_t)Nw * H_C;        // word feats (persist)
    float* h1 = ws + o; o += (size_t)N * OUT_C;       // ent layer-1 out
    o = (o + 3) & ~(size_t)3;
    unsigned short* AbfF = (unsigned short*)(ws + o); o += ((size_t)M * 448) / 2;  // final concat [ctx||Q||pad]
    o = (o + 3) & ~(size_t)3;
    float* BIG = ws + o;                              // phase-local (10.4M floats)
    float* wh1 = BIG;                                 // phase W: 6M
    unsigned short* AbfW = (unsigned short*)(BIG + (size_t)Nw * H_C);  // phase W: Nw*224 ush
    unsigned short* AbfE = (unsigned short*)BIG;      // phase E: N*416 ush
    float* QA = (float*)d_out;                        // phase A: M*200 (dead before final memset)

    // =============== CSR build (both graphs) ===============
    hipMemsetAsync(wdeg, 0, (size_t)Nw * 4, stream);
    hipMemsetAsync(edeg, 0, (size_t)N * 4, stream);
    hist_k<<<ew_grid(Ew), 256, 0, stream>>>(wdst, wdeg, Ew);
    hist_k<<<ew_grid(E), 256, 0, stream>>>(edge_dst, edeg, E);
    {
        int nbW = (Nw + 255) / 256;
        scanA_k<<<nbW, 256, 0, stream>>>(wdeg, bsum, Nw);
        scanB_k<<<1, 256, 0, stream>>>(bsum, nbW);
        scanC_k<<<nbW, 256, 0, stream>>>(wdeg, bsum, woffs, wcur, Nw);
        fill_k<<<ew_grid(Ew), 256, 0, stream>>>(wdst, wcur, wbkt, Ew);
        int nbE = (N + 255) / 256;
        scanA_k<<<nbE, 256, 0, stream>>>(edeg, bsum, N);
        scanB_k<<<1, 256, 0, stream>>>(bsum, nbE);
        scanC_k<<<nbE, 256, 0, stream>>>(edeg, bsum, eoffs, ecur, N);
        fill_k<<<ew_grid(E), 256, 0, stream>>>(edge_dst, ecur, ebkt, E);
    }
    // rel chains (f32, tiny)
    gemm_f32_k<<<dim3((NREL_C + 63) / 64, (OUT_C + 63) / 64), 256, 0, stream>>>(
        rel_embeds, cg1_wr, rel1, NREL_C, OUT_C, H_C);
    gemm_f32_k<<<dim3((NREL_C + 63) / 64, (H_C + 63) / 64), 256, 0, stream>>>(
        rel1, cg2_wr, rel2, NREL_C, H_C, OUT_C);

    // =============== phase W: word GCN ===============
    // L1: Abf = mean(word_embeds[word_id[wsrc]]) over wdst   [30000 x 128]
    gather_mean_k<OUT_C, 0, 128, 1, false, false><<<dim3((Nw + 3) / 4), 256, 0, stream>>>(
        word_embeds, nullptr, nullptr, wsrc, nullptr, word_id, woffs, wdeg, wbkt, AbfW, Nw);
    convW_k<<<ew_grid(208 * 128), 256, 0, stream>>>(gcn_w1, OUT_C, nullptr, 0, H_C, Wt, 208, 128);
    launch_mfma<13, 1, false, false>(stream, AbfW, 128, Wt, gcn_b1, wh1, H_C, nullptr, Nw, H_C, 128);
    // L2: Abf = mean(wh1[wsrc]) over wdst   [30000 x 224]
    gather_mean_k<H_C, 0, 224, 0, false, false><<<dim3((Nw + 3) / 4), 256, 0, stream>>>(
        wh1, nullptr, nullptr, wsrc, nullptr, nullptr, woffs, wdeg, wbkt, AbfW, Nw);
    convW_k<<<ew_grid(208 * 224), 256, 0, stream>>>(gcn_w2, H_C, nullptr, 0, H_C, Wt, 208, 224);
    launch_mfma<13, 1, false, false>(stream, AbfW, 224, Wt, gcn_b2, wh, H_C, nullptr, Nw, H_C, 224);

    // =============== phase E: CompGCN ===============
    // L1: Abf = [mean(ent[src%10k] - rel[type]) || ent[n%10k]]   [50000 x 416]
    gather_mean_k<H_C, H_C, 416, 2, true, true><<<dim3((N + 3) / 4), 256, 0, stream>>>(
        ent_embeds, ent_embeds, rel_embeds, edge_src, edge_type, nullptr,
        eoffs, edeg, ebkt, AbfE, N);
    convW_k<<<ew_grid(112 * 416), 256, 0, stream>>>(cg1_wn, H_C, cg1_wl, H_C, OUT_C, Wt, 112, 416);
    launch_mfma<7, 1, false, false>(stream, AbfE, 416, Wt, nullptr, h1, OUT_C, nullptr, N, OUT_C, 416);
    // L2: Abf = [mean(h1[src] - rel1[type]) || h1[n]]   [50000 x 224]
    gather_mean_k<OUT_C, OUT_C, 224, 0, true, false><<<dim3((N + 3) / 4), 256, 0, stream>>>(
        h1, h1, rel1, edge_src, edge_type, nullptr, eoffs, edeg, ebkt, AbfE, N);
    convW_k<<<ew_grid(208 * 224), 256, 0, stream>>>(cg2_wn, OUT_C, cg2_wl, OUT_C, H_C, Wt, 208, 224);
    // h2 -> bf16 directly into AbfF cols [200,400), rows [0,N)
    launch_mfma<13, 1, false, true>(stream, AbfE, 224, Wt, nullptr, AbfF + 200, 448, nullptr, N, H_C, 224);

    // =============== phase A: attention + output ===============
    build_q_bf16_k<<<ew_grid((size_t)Rsel * H_C), 256, 0, stream>>>(
        rel2, edge_type, r_ids_graph, AbfF, N, M);
    zero_pad_k<<<ew_grid((size_t)M * 6), 256, 0, stream>>>(AbfF, M);
    rowoff_k<<<ew_grid(M), 256, 0, stream>>>(node_slot, edge_slot, rowOff, N, M, divq, per, embBase);
    // QA = Q @ wa   (A = AbfF cols 200..424, lda=448)
    convW_k<<<ew_grid(208 * 224), 256, 0, stream>>>(attn_wa, H_C, nullptr, 0, H_C, Wt, 208, 224);
    launch_mfma<13, 0, false, false>(stream, AbfF + 200, 448, Wt, nullptr, QA, H_C, nullptr, M, H_C, 224);
    // attention -> ctx bf16 into AbfF cols [0,200)
    attn_k<<<(M + 3) / 4, 256, 0, stream>>>(QA, wh, ent_word_idx, ent_word_mask,
                                            rel_word_idx, rel_word_mask, AbfF, N, M);
    // final: out = tanh([ctx||Q] @ wc) scattered into zeroed d_out
    hipMemsetAsync(d_out, 0, (size_t)out_size * 4, stream);
    convW_k<<<ew_grid(208 * 416), 256, 0, stream>>>(attn_wc, H_C, attn_wc + (size_t)H_C * H_C,
                                                    H_C, H_C, Wt, 208, 416);
    launch_mfma<13, 2, true, false>(stream, AbfF, 448, Wt, nullptr, d_out, H_C, rowOff, M, H_C, 416);
}